// Round 1
// baseline (362.713 us; speedup 1.0000x reference)
//
#include <hip/hip_runtime.h>
#include <hip/hip_bf16.h>
#include <math.h>

#define NB 16
#define NL 2048
#define ND 128
#define QT 64
#define KT 32
#define NEGV -1000000.0f
#define SCL 0.08838834764831845f  // 1/sqrt(128)

typedef short bfrag __attribute__((ext_vector_type(8)));   // 8 bf16 as shorts (MFMA A/B frag)
typedef float f32x4 __attribute__((ext_vector_type(4)));
typedef short s16x4 __attribute__((ext_vector_type(4)));

// round-to-nearest-even fp32 -> bf16 (bit pattern in a short)
__device__ __forceinline__ short f2bf(float f) {
    unsigned u = __float_as_uint(f);
    unsigned r = u + 0x7FFFu + ((u >> 16) & 1u);
    return (short)(r >> 16);
}
__device__ __forceinline__ float bf2f(short h) {
    return __uint_as_float(((unsigned)(unsigned short)h) << 16);
}

// LDS swizzles (element-index space; XOR at 8-elem = 16B granularity)
__device__ __forceinline__ int kswz(int r, int c) { return (r * ND + c) ^ ((r & 7) << 3); }
__device__ __forceinline__ int vswz(int d, int k) { return (d * KT + k) ^ (((d >> 1) & 3) << 3); }
__device__ __forceinline__ int pswz(int q, int k) { return (q * KT + k) ^ (((q >> 1) & 3) << 3); }

__global__ __launch_bounds__(256, 2) void attn_fwd(
    const float* __restrict__ Qg, const float* __restrict__ Kg,
    const float* __restrict__ Vg, const int* __restrict__ vlens,
    float* __restrict__ Og)
{
    // K tile row-major [KT][ND], V tile transposed [ND][KT], P per-wave [16][KT]; all hi/lo bf16
    __shared__ __align__(16) short kh[KT * ND], kl[KT * ND];
    __shared__ __align__(16) short vth[ND * KT], vtl[ND * KT];
    __shared__ __align__(16) short ph[4][16 * KT], pl[4][16 * KT];

    const int tid = threadIdx.x;
    const int wv = tid >> 6, lane = tid & 63;
    const int lq = lane & 15, lg = lane >> 4;

    const int bid = blockIdx.x;
    const int b = bid >> 5;            // 32 q-blocks per batch
    const int qblk = bid & 31;
    const int q0 = qblk * QT + wv * 16;  // this wave's 16 q rows

    const int vlen = vlens[b];
    const int kmax = (vlen > 0) ? vlen : NL;   // vlen==0 -> uniform softmax over ALL keys
    const int ntiles = (kmax + KT - 1) / KT;

    // ---- Q fragments in registers, split hi/lo. B-operand layout:
    // lane holds Q[q0+lq][s*32 + lg*8 + j], j=0..7 contiguous.
    bfrag qh[4], ql[4];
    {
        const float* qp = Qg + ((size_t)b * NL + (size_t)(q0 + lq)) * ND + lg * 8;
        #pragma unroll
        for (int s = 0; s < 4; ++s) {
            f32x4 a0 = *(const f32x4*)(qp + s * 32);
            f32x4 a1 = *(const f32x4*)(qp + s * 32 + 4);
            float vals[8] = {a0[0], a0[1], a0[2], a0[3], a1[0], a1[1], a1[2], a1[3]};
            bfrag h, l;
            #pragma unroll
            for (int j = 0; j < 8; ++j) {
                short hb = f2bf(vals[j]);
                h[j] = hb;
                l[j] = f2bf(vals[j] - bf2f(hb));
            }
            qh[s] = h; ql[s] = l;
        }
    }

    const f32x4 zero4 = {0.f, 0.f, 0.f, 0.f};
    float m_run = -INFINITY, l_run = 0.0f;
    f32x4 oacc[8];
    #pragma unroll
    for (int i = 0; i < 8; ++i) oacc[i] = zero4;

    const float* kbase = Kg + (size_t)b * NL * ND;
    const float* vbase = Vg + (size_t)b * NL * ND;

    for (int t = 0; t < ntiles; ++t) {
        const int kt0 = t * KT;
        __syncthreads();   // all waves done reading previous tile's K/V

        // ---- stage K tile (hi/lo), 1024 float4 tasks over 256 threads
        #pragma unroll
        for (int i = 0; i < 4; ++i) {
            int f = i * 256 + tid;
            int r = f >> 5, c4 = (f & 31) << 2;
            f32x4 v = *(const f32x4*)(kbase + (size_t)(kt0 + r) * ND + c4);
            s16x4 hh, ll;
            #pragma unroll
            for (int j = 0; j < 4; ++j) {
                short hb = f2bf(v[j]);
                hh[j] = hb;
                ll[j] = f2bf(v[j] - bf2f(hb));
            }
            int idx = kswz(r, c4);
            *(s16x4*)&kh[idx] = hh;
            *(s16x4*)&kl[idx] = ll;
        }
        // ---- stage V transposed: task (c,kq) reads V[kt0+kq..+3][c] (coalesced across lanes in c)
        #pragma unroll
        for (int i = 0; i < 4; ++i) {
            int tau = i * 256 + tid;
            int c = tau & 127, kq = (tau >> 7) << 2;
            s16x4 hh, ll;
            #pragma unroll
            for (int j = 0; j < 4; ++j) {
                float fv = vbase[(size_t)(kt0 + kq + j) * ND + c];
                short hb = f2bf(fv);
                hh[j] = hb;
                ll[j] = f2bf(fv - bf2f(hb));
            }
            int idx = vswz(c, kq);
            *(s16x4*)&vth[idx] = hh;
            *(s16x4*)&vtl[idx] = ll;
        }
        __syncthreads();

        // ---- QK^T (swapped): S^T[k][q] = sum_d K[k][d] Q[q][d], 2 sub-tiles of 16 k
        // split: Kh*Qh + Kl*Qh + Kh*Ql
        f32x4 sacc[2];
        sacc[0] = zero4; sacc[1] = zero4;
        #pragma unroll
        for (int sub = 0; sub < 2; ++sub) {
            #pragma unroll
            for (int s = 0; s < 4; ++s) {
                int ia = kswz(sub * 16 + lq, s * 32 + lg * 8);
                bfrag ah = *(const bfrag*)&kh[ia];
                bfrag al = *(const bfrag*)&kl[ia];
                sacc[sub] = __builtin_amdgcn_mfma_f32_16x16x32_bf16(ah, qh[s], sacc[sub], 0, 0, 0);
                sacc[sub] = __builtin_amdgcn_mfma_f32_16x16x32_bf16(al, qh[s], sacc[sub], 0, 0, 0);
                sacc[sub] = __builtin_amdgcn_mfma_f32_16x16x32_bf16(ah, ql[s], sacc[sub], 0, 0, 0);
            }
        }

        // ---- scale + mask (exact -1e6 like reference), online softmax
        // lane's element: k_local = sub*16 + lg*4 + r, q = lq
        float sv[2][4];
        float tmax = -INFINITY;
        #pragma unroll
        for (int sub = 0; sub < 2; ++sub)
            #pragma unroll
            for (int r = 0; r < 4; ++r) {
                int kg = kt0 + sub * 16 + lg * 4 + r;
                float x = (kg < vlen) ? sacc[sub][r] * SCL : NEGV;
                sv[sub][r] = x;
                tmax = fmaxf(tmax, x);
            }
        tmax = fmaxf(tmax, __shfl_xor(tmax, 16, 64));
        tmax = fmaxf(tmax, __shfl_xor(tmax, 32, 64));
        float m_new = fmaxf(m_run, tmax);
        float corr = expf(m_run - m_new);    // first tile: exp(-inf)=0
        float rsum = 0.f;
        s16x4 phv[2], plv[2];
        #pragma unroll
        for (int sub = 0; sub < 2; ++sub)
            #pragma unroll
            for (int r = 0; r < 4; ++r) {
                float p = expf(sv[sub][r] - m_new);  // masked -> exactly 0 (or 1 if all masked)
                rsum += p;
                short hb = f2bf(p);
                phv[sub][r] = hb;
                plv[sub][r] = f2bf(p - bf2f(hb));
            }
        rsum += __shfl_xor(rsum, 16, 64);
        rsum += __shfl_xor(rsum, 32, 64);
        l_run = l_run * corr + rsum;
        m_run = m_new;
        #pragma unroll
        for (int i = 0; i < 8; ++i) {
            oacc[i][0] *= corr; oacc[i][1] *= corr;
            oacc[i][2] *= corr; oacc[i][3] *= corr;
        }

        // ---- P -> per-wave LDS (layout P[q][k], hi/lo)
        #pragma unroll
        for (int sub = 0; sub < 2; ++sub) {
            int ip = pswz(lq, sub * 16 + lg * 4);
            *(s16x4*)&ph[wv][ip] = phv[sub];
            *(s16x4*)&pl[wv][ip] = plv[sub];
        }

        // ---- PV (swapped): O^T[d][q] += sum_k V^T[d][k] P^T[k][q]
        // split: Vh*Ph + Vl*Ph + Vh*Pl
        int ipb = pswz(lq, lg * 8);
        bfrag pbh = *(const bfrag*)&ph[wv][ipb];
        bfrag pbl = *(const bfrag*)&pl[wv][ipb];
        #pragma unroll
        for (int dt = 0; dt < 8; ++dt) {
            int iv = vswz(dt * 16 + lq, lg * 8);
            bfrag vh  = *(const bfrag*)&vth[iv];
            bfrag vlo = *(const bfrag*)&vtl[iv];
            oacc[dt] = __builtin_amdgcn_mfma_f32_16x16x32_bf16(vh,  pbh, oacc[dt], 0, 0, 0);
            oacc[dt] = __builtin_amdgcn_mfma_f32_16x16x32_bf16(vlo, pbh, oacc[dt], 0, 0, 0);
            oacc[dt] = __builtin_amdgcn_mfma_f32_16x16x32_bf16(vh,  pbl, oacc[dt], 0, 0, 0);
        }
    }

    // ---- epilogue: O[q][d] = oacc^T / l_run; lane holds d = dt*16 + lg*4 + r for q = lq
    float inv = 1.0f / l_run;   // >= 1 always (max element contributes 1; all-masked -> 2048)
    float* op = Og + ((size_t)b * NL + (size_t)(q0 + lq)) * ND + lg * 4;
    #pragma unroll
    for (int dt = 0; dt < 8; ++dt) {
        f32x4 o;
        o[0] = oacc[dt][0] * inv; o[1] = oacc[dt][1] * inv;
        o[2] = oacc[dt][2] * inv; o[3] = oacc[dt][3] * inv;
        *(f32x4*)(op + dt * 16) = o;
    }
}

extern "C" void kernel_launch(void* const* d_in, const int* in_sizes, int n_in,
                              void* d_out, int out_size, void* d_ws, size_t ws_size,
                              hipStream_t stream) {
    (void)in_sizes; (void)n_in; (void)out_size; (void)d_ws; (void)ws_size;
    const float* Q = (const float*)d_in[0];
    const float* K = (const float*)d_in[1];
    const float* V = (const float*)d_in[2];
    const int* vl  = (const int*)d_in[3];
    float* O = (float*)d_out;
    dim3 grid(NB * (NL / QT));   // 512 blocks, 4 waves each
    dim3 block(256);
    attn_fwd<<<grid, block, 0, stream>>>(Q, K, V, vl, O);
}

// Round 2
// 193.019 us; speedup vs baseline: 1.8792x; 1.8792x over previous
//
#include <hip/hip_runtime.h>
#include <hip/hip_bf16.h>
#include <math.h>

#define NB 16
#define NL 2048
#define ND 128
#define QT 64
#define KT 32
#define NTILE (NL / KT)            // 64 tiles per batch
#define NEGV -1000000.0f
#define SCL 0.08838834764831845f   // 1/sqrt(128)

typedef short bfrag __attribute__((ext_vector_type(8)));   // 8 bf16 (MFMA A/B frag)
typedef float f32x4 __attribute__((ext_vector_type(4)));
typedef short s16x4 __attribute__((ext_vector_type(4)));
typedef short s16x8 __attribute__((ext_vector_type(8)));

typedef const __attribute__((address_space(1))) void* gas_ptr;
typedef __attribute__((address_space(3))) void* las_ptr;

// round-to-nearest-even fp32 -> bf16 bits
__device__ __forceinline__ short f2bf(float f) {
    unsigned u = __float_as_uint(f);
    unsigned r = u + 0x7FFFu + ((u >> 16) & 1u);
    return (short)(r >> 16);
}
__device__ __forceinline__ float bf2f(short h) {
    return __uint_as_float(((unsigned)(unsigned short)h) << 16);
}

// LDS swizzles (element-index space; XOR at 8-elem = 16B granularity)
__device__ __forceinline__ int kswz(int r, int c) { return (r * ND + c) ^ ((r & 7) << 3); }
__device__ __forceinline__ int vswz(int d, int k) { return (d * KT + k) ^ (((d >> 1) & 3) << 3); }
__device__ __forceinline__ int pswz(int q, int k) { return (q * KT + k) ^ (((q >> 1) & 3) << 3); }

// ===================== prep: K -> swizzled hi/lo bf16 tiles =====================
// KWS layout: [b][t][hl][4096] shorts, tile content[kswz(r,c)] = bf16(K[r][c])
__global__ __launch_bounds__(512) void prep_k(const float* __restrict__ Kg,
                                              short* __restrict__ KWS) {
    const int bt = blockIdx.x;          // b*64 + t
    const int g = threadIdx.x;          // one 16B chunk (8 elems)
    const int r = g >> 4, ccd = g & 15;
    const int ccs = ccd ^ (r & 7);      // inverse swizzle on the SOURCE
    const float* src = Kg + ((size_t)((bt >> 6) * NL) + (bt & 63) * KT + r) * ND + ccs * 8;
    f32x4 a0 = *(const f32x4*)src;
    f32x4 a1 = *(const f32x4*)(src + 4);
    float vals[8] = {a0[0], a0[1], a0[2], a0[3], a1[0], a1[1], a1[2], a1[3]};
    s16x8 h, l;
    #pragma unroll
    for (int j = 0; j < 8; ++j) {
        short hb = f2bf(vals[j]);
        h[j] = hb;
        l[j] = f2bf(vals[j] - bf2f(hb));
    }
    short* dst = KWS + (size_t)bt * 2 * 4096 + g * 8;
    *(s16x8*)dst = h;
    *(s16x8*)(dst + 4096) = l;
}

// ===================== prep: V -> transposed swizzled hi/lo tiles ===============
// VWS layout: [b][t][hl][4096] shorts, tile content[vswz(d,k)] = bf16(V[kt0+k][d])
__global__ __launch_bounds__(512) void prep_v(const float* __restrict__ Vg,
                                              short* __restrict__ VWS) {
    const int bt = blockIdx.x;
    const int g = threadIdx.x;          // g = ch*128 + d  (coalesced reads over d)
    const int ch = g >> 7, d = g & 127;
    const int chs = ch ^ ((d >> 1) & 3);
    const float* src = Vg + ((size_t)((bt >> 6) * NL) + (bt & 63) * KT + chs * 8) * ND + d;
    s16x8 h, l;
    #pragma unroll
    for (int j = 0; j < 8; ++j) {
        float f = src[(size_t)j * ND];
        short hb = f2bf(f);
        h[j] = hb;
        l[j] = f2bf(f - bf2f(hb));
    }
    short* dst = VWS + (size_t)bt * 2 * 4096 + (d * 4 + ch) * 8;
    *(s16x8*)dst = h;
    *(s16x8*)(dst + 4096) = l;
}

// ===================== main: double-buffered flash attention =====================
__global__ __launch_bounds__(256, 2) void attn_fwd(
    const float* __restrict__ Qg, const int* __restrict__ vlens,
    const short* __restrict__ KWS, const short* __restrict__ VWS,
    float* __restrict__ Og)
{
    __shared__ __align__(16) short kv[2][4][4096];     // [buf][kh,kl,vh,vl] 64 KB
    __shared__ __align__(16) short ph[4][512], pl[4][512];  // per-wave P hi/lo, 8 KB

    const int tid = threadIdx.x;
    const int wv = tid >> 6, lane = tid & 63;
    const int lq = lane & 15, lg = lane >> 4;

    // XCD-aware swizzle: XCD x hosts batches {2x, 2x+1} -> K/V ws fits its L2
    const int bid = blockIdx.x;
    const int xcd = bid & 7, slot = bid >> 3;          // slot 0..63
    const int b = xcd * 2 + (slot >> 5);
    const int qblk = slot & 31;
    const int q0 = qblk * QT + wv * 16;

    const int vlen = vlens[b];
    const int kmax = (vlen > 0) ? vlen : NL;           // vlen==0 -> uniform over all keys
    const int ntiles = (kmax + KT - 1) / KT;

    // ---- Q fragments hi/lo: lane holds Q[q0+lq][s*32 + lg*8 + j]
    bfrag qh[4], ql[4];
    {
        const float* qp = Qg + ((size_t)b * NL + (size_t)(q0 + lq)) * ND + lg * 8;
        #pragma unroll
        for (int s = 0; s < 4; ++s) {
            f32x4 a0 = *(const f32x4*)(qp + s * 32);
            f32x4 a1 = *(const f32x4*)(qp + s * 32 + 4);
            float vals[8] = {a0[0], a0[1], a0[2], a0[3], a1[0], a1[1], a1[2], a1[3]};
            bfrag h, l;
            #pragma unroll
            for (int j = 0; j < 8; ++j) {
                short hb = f2bf(vals[j]);
                h[j] = hb;
                l[j] = f2bf(vals[j] - bf2f(hb));
            }
            qh[s] = h; ql[s] = l;
        }
    }

    const short* kws = KWS + (size_t)b * NTILE * 2 * 4096;
    const short* vws = VWS + (size_t)b * NTILE * 2 * 4096;

    // wave wv stages array wv: 0=kh 1=kl 2=vh 3=vl; 8 x 16B-per-lane async loads
    const short* src_base = (wv < 2 ? kws : vws);
    const int hl = wv & 1;

    const f32x4 zero4 = {0.f, 0.f, 0.f, 0.f};
    float m_run = -INFINITY, l_run = 0.0f;
    f32x4 oacc[8];
    #pragma unroll
    for (int i = 0; i < 8; ++i) oacc[i] = zero4;

    int cur = 0;
    // prologue: stage tile 0 into buf 0
    {
        const short* s0 = src_base + (size_t)hl * 4096 + lane * 8;
        #pragma unroll
        for (int i = 0; i < 8; ++i)
            __builtin_amdgcn_global_load_lds((gas_ptr)(s0 + i * 512),
                                             (las_ptr)(&kv[0][wv][i * 512]), 16, 0, 0);
    }

    for (int t = 0; t < ntiles; ++t) {
        const int kt0 = t * KT;
        if (t + 1 < ntiles) {
            // prefetch next tile into the other buffer (issued, NOT waited)
            const short* sn = src_base + ((size_t)(t + 1) * 2 + hl) * 4096 + lane * 8;
            #pragma unroll
            for (int i = 0; i < 8; ++i)
                __builtin_amdgcn_global_load_lds((gas_ptr)(sn + i * 512),
                                                 (las_ptr)(&kv[cur ^ 1][wv][i * 512]), 16, 0, 0);
            asm volatile("s_waitcnt vmcnt(8)" ::: "memory");  // current tile's 8 done
        } else {
            asm volatile("s_waitcnt vmcnt(0)" ::: "memory");
        }
        __builtin_amdgcn_s_barrier();
        asm volatile("" ::: "memory");

        const short* khp = &kv[cur][0][0];
        const short* klp = &kv[cur][1][0];
        const short* vhp = &kv[cur][2][0];
        const short* vlp = &kv[cur][3][0];

        // ---- QK^T (swapped): S^T[k][q]; split KhQh + KlQh + KhQl
        f32x4 sacc[2];
        sacc[0] = zero4; sacc[1] = zero4;
        #pragma unroll
        for (int sub = 0; sub < 2; ++sub) {
            #pragma unroll
            for (int s = 0; s < 4; ++s) {
                int ia = kswz(sub * 16 + lq, s * 32 + lg * 8);
                bfrag ah = *(const bfrag*)&khp[ia];
                bfrag al = *(const bfrag*)&klp[ia];
                sacc[sub] = __builtin_amdgcn_mfma_f32_16x16x32_bf16(ah, qh[s], sacc[sub], 0, 0, 0);
                sacc[sub] = __builtin_amdgcn_mfma_f32_16x16x32_bf16(al, qh[s], sacc[sub], 0, 0, 0);
                sacc[sub] = __builtin_amdgcn_mfma_f32_16x16x32_bf16(ah, ql[s], sacc[sub], 0, 0, 0);
            }
        }

        // ---- scale + exact -1e6 mask + online softmax (k = sub*16 + lg*4 + r, q = lq)
        float sv[2][4];
        float tmax = -INFINITY;
        #pragma unroll
        for (int sub = 0; sub < 2; ++sub)
            #pragma unroll
            for (int r = 0; r < 4; ++r) {
                int kg = kt0 + sub * 16 + lg * 4 + r;
                float x = (kg < vlen) ? sacc[sub][r] * SCL : NEGV;
                sv[sub][r] = x;
                tmax = fmaxf(tmax, x);
            }
        tmax = fmaxf(tmax, __shfl_xor(tmax, 16, 64));
        tmax = fmaxf(tmax, __shfl_xor(tmax, 32, 64));
        float m_new = fmaxf(m_run, tmax);
        float corr = __expf(m_run - m_new);   // first tile: exp(-inf)=0
        float rsum = 0.f;
        s16x4 phv[2], plv[2];
        #pragma unroll
        for (int sub = 0; sub < 2; ++sub)
            #pragma unroll
            for (int r = 0; r < 4; ++r) {
                float p = __expf(sv[sub][r] - m_new);
                rsum += p;
                short hb = f2bf(p);
                phv[sub][r] = hb;
                plv[sub][r] = f2bf(p - bf2f(hb));
            }
        rsum += __shfl_xor(rsum, 16, 64);
        rsum += __shfl_xor(rsum, 32, 64);
        l_run = l_run * corr + rsum;
        m_run = m_new;
        #pragma unroll
        for (int i = 0; i < 8; ++i) {
            oacc[i][0] *= corr; oacc[i][1] *= corr;
            oacc[i][2] *= corr; oacc[i][3] *= corr;
        }

        // ---- P -> per-wave LDS (hi/lo), then read back as PV B-operand
        #pragma unroll
        for (int sub = 0; sub < 2; ++sub) {
            int ip = pswz(lq, sub * 16 + lg * 4);
            *(s16x4*)&ph[wv][ip] = phv[sub];
            *(s16x4*)&pl[wv][ip] = plv[sub];
        }
        int ipb = pswz(lq, lg * 8);
        bfrag pbh = *(const bfrag*)&ph[wv][ipb];
        bfrag pbl = *(const bfrag*)&pl[wv][ipb];

        // ---- PV (swapped): O^T[d][q] += V^T hi/lo x P hi/lo (3 terms)
        #pragma unroll
        for (int dt = 0; dt < 8; ++dt) {
            int iv = vswz(dt * 16 + lq, lg * 8);
            bfrag vh  = *(const bfrag*)&vhp[iv];
            bfrag vlo = *(const bfrag*)&vlp[iv];
            oacc[dt] = __builtin_amdgcn_mfma_f32_16x16x32_bf16(vh,  pbh, oacc[dt], 0, 0, 0);
            oacc[dt] = __builtin_amdgcn_mfma_f32_16x16x32_bf16(vlo, pbh, oacc[dt], 0, 0, 0);
            oacc[dt] = __builtin_amdgcn_mfma_f32_16x16x32_bf16(vh,  pbl, oacc[dt], 0, 0, 0);
        }

        asm volatile("" ::: "memory");
        __builtin_amdgcn_s_barrier();   // all waves done reading kv[cur]
        cur ^= 1;
    }

    // ---- epilogue: O[q][d] = oacc^T / l_run; lane holds d = dt*16 + lg*4 + r, q = lq
    float inv = 1.0f / l_run;
    float* op = Og + ((size_t)b * NL + (size_t)(q0 + lq)) * ND + lg * 4;
    #pragma unroll
    for (int dt = 0; dt < 8; ++dt) {
        f32x4 o;
        o[0] = oacc[dt][0] * inv; o[1] = oacc[dt][1] * inv;
        o[2] = oacc[dt][2] * inv; o[3] = oacc[dt][3] * inv;
        *(f32x4*)(op + dt * 16) = o;
    }
}

// ===================== fallback (round-1 kernel, used if ws too small) ===========
__global__ __launch_bounds__(256, 2) void attn_fwd_fb(
    const float* __restrict__ Qg, const float* __restrict__ Kg,
    const float* __restrict__ Vg, const int* __restrict__ vlens,
    float* __restrict__ Og)
{
    __shared__ __align__(16) short kh[KT * ND], kl[KT * ND];
    __shared__ __align__(16) short vth[ND * KT], vtl[ND * KT];
    __shared__ __align__(16) short ph[4][16 * KT], pl[4][16 * KT];

    const int tid = threadIdx.x;
    const int wv = tid >> 6, lane = tid & 63;
    const int lq = lane & 15, lg = lane >> 4;
    const int bid = blockIdx.x;
    const int b = bid >> 5;
    const int qblk = bid & 31;
    const int q0 = qblk * QT + wv * 16;
    const int vlen = vlens[b];
    const int kmax = (vlen > 0) ? vlen : NL;
    const int ntiles = (kmax + KT - 1) / KT;

    bfrag qh[4], ql[4];
    {
        const float* qp = Qg + ((size_t)b * NL + (size_t)(q0 + lq)) * ND + lg * 8;
        #pragma unroll
        for (int s = 0; s < 4; ++s) {
            f32x4 a0 = *(const f32x4*)(qp + s * 32);
            f32x4 a1 = *(const f32x4*)(qp + s * 32 + 4);
            float vals[8] = {a0[0], a0[1], a0[2], a0[3], a1[0], a1[1], a1[2], a1[3]};
            bfrag h, l;
            #pragma unroll
            for (int j = 0; j < 8; ++j) {
                short hb = f2bf(vals[j]);
                h[j] = hb;
                l[j] = f2bf(vals[j] - bf2f(hb));
            }
            qh[s] = h; ql[s] = l;
        }
    }

    const f32x4 zero4 = {0.f, 0.f, 0.f, 0.f};
    float m_run = -INFINITY, l_run = 0.0f;
    f32x4 oacc[8];
    #pragma unroll
    for (int i = 0; i < 8; ++i) oacc[i] = zero4;

    const float* kbase = Kg + (size_t)b * NL * ND;
    const float* vbase = Vg + (size_t)b * NL * ND;

    for (int t = 0; t < ntiles; ++t) {
        const int kt0 = t * KT;
        __syncthreads();
        #pragma unroll
        for (int i = 0; i < 4; ++i) {
            int f = i * 256 + tid;
            int r = f >> 5, c4 = (f & 31) << 2;
            f32x4 v = *(const f32x4*)(kbase + (size_t)(kt0 + r) * ND + c4);
            s16x4 hh, ll;
            #pragma unroll
            for (int j = 0; j < 4; ++j) {
                short hb = f2bf(v[j]);
                hh[j] = hb;
                ll[j] = f2bf(v[j] - bf2f(hb));
            }
            int idx = kswz(r, c4);
            *(s16x4*)&kh[idx] = hh;
            *(s16x4*)&kl[idx] = ll;
        }
        #pragma unroll
        for (int i = 0; i < 4; ++i) {
            int tau = i * 256 + tid;
            int c = tau & 127, kq = (tau >> 7) << 2;
            s16x4 hh, ll;
            #pragma unroll
            for (int j = 0; j < 4; ++j) {
                float fv = vbase[(size_t)(kt0 + kq + j) * ND + c];
                short hb = f2bf(fv);
                hh[j] = hb;
                ll[j] = f2bf(fv - bf2f(hb));
            }
            int idx = vswz(c, kq);
            *(s16x4*)&vth[idx] = hh;
            *(s16x4*)&vtl[idx] = ll;
        }
        __syncthreads();

        f32x4 sacc[2];
        sacc[0] = zero4; sacc[1] = zero4;
        #pragma unroll
        for (int sub = 0; sub < 2; ++sub) {
            #pragma unroll
            for (int s = 0; s < 4; ++s) {
                int ia = kswz(sub * 16 + lq, s * 32 + lg * 8);
                bfrag ah = *(const bfrag*)&kh[ia];
                bfrag al = *(const bfrag*)&kl[ia];
                sacc[sub] = __builtin_amdgcn_mfma_f32_16x16x32_bf16(ah, qh[s], sacc[sub], 0, 0, 0);
                sacc[sub] = __builtin_amdgcn_mfma_f32_16x16x32_bf16(al, qh[s], sacc[sub], 0, 0, 0);
                sacc[sub] = __builtin_amdgcn_mfma_f32_16x16x32_bf16(ah, ql[s], sacc[sub], 0, 0, 0);
            }
        }

        float sv[2][4];
        float tmax = -INFINITY;
        #pragma unroll
        for (int sub = 0; sub < 2; ++sub)
            #pragma unroll
            for (int r = 0; r < 4; ++r) {
                int kg = kt0 + sub * 16 + lg * 4 + r;
                float x = (kg < vlen) ? sacc[sub][r] * SCL : NEGV;
                sv[sub][r] = x;
                tmax = fmaxf(tmax, x);
            }
        tmax = fmaxf(tmax, __shfl_xor(tmax, 16, 64));
        tmax = fmaxf(tmax, __shfl_xor(tmax, 32, 64));
        float m_new = fmaxf(m_run, tmax);
        float corr = __expf(m_run - m_new);
        float rsum = 0.f;
        s16x4 phv[2], plv[2];
        #pragma unroll
        for (int sub = 0; sub < 2; ++sub)
            #pragma unroll
            for (int r = 0; r < 4; ++r) {
                float p = __expf(sv[sub][r] - m_new);
                rsum += p;
                short hb = f2bf(p);
                phv[sub][r] = hb;
                plv[sub][r] = f2bf(p - bf2f(hb));
            }
        rsum += __shfl_xor(rsum, 16, 64);
        rsum += __shfl_xor(rsum, 32, 64);
        l_run = l_run * corr + rsum;
        m_run = m_new;
        #pragma unroll
        for (int i = 0; i < 8; ++i) {
            oacc[i][0] *= corr; oacc[i][1] *= corr;
            oacc[i][2] *= corr; oacc[i][3] *= corr;
        }

        #pragma unroll
        for (int sub = 0; sub < 2; ++sub) {
            int ip = pswz(lq, sub * 16 + lg * 4);
            *(s16x4*)&ph[wv][ip] = phv[sub];
            *(s16x4*)&pl[wv][ip] = plv[sub];
        }
        int ipb = pswz(lq, lg * 8);
        bfrag pbh = *(const bfrag*)&ph[wv][ipb];
        bfrag pbl = *(const bfrag*)&pl[wv][ipb];
        #pragma unroll
        for (int dt = 0; dt < 8; ++dt) {
            int iv = vswz(dt * 16 + lq, lg * 8);
            bfrag vh  = *(const bfrag*)&vth[iv];
            bfrag vlo = *(const bfrag*)&vtl[iv];
            oacc[dt] = __builtin_amdgcn_mfma_f32_16x16x32_bf16(vh,  pbh, oacc[dt], 0, 0, 0);
            oacc[dt] = __builtin_amdgcn_mfma_f32_16x16x32_bf16(vlo, pbh, oacc[dt], 0, 0, 0);
            oacc[dt] = __builtin_amdgcn_mfma_f32_16x16x32_bf16(vh,  pbl, oacc[dt], 0, 0, 0);
        }
    }

    float inv = 1.0f / l_run;
    float* op = Og + ((size_t)b * NL + (size_t)(q0 + lq)) * ND + lg * 4;
    #pragma unroll
    for (int dt = 0; dt < 8; ++dt) {
        f32x4 o;
        o[0] = oacc[dt][0] * inv; o[1] = oacc[dt][1] * inv;
        o[2] = oacc[dt][2] * inv; o[3] = oacc[dt][3] * inv;
        *(f32x4*)(op + dt * 16) = o;
    }
}

extern "C" void kernel_launch(void* const* d_in, const int* in_sizes, int n_in,
                              void* d_out, int out_size, void* d_ws, size_t ws_size,
                              hipStream_t stream) {
    (void)in_sizes; (void)n_in; (void)out_size;
    const float* Q = (const float*)d_in[0];
    const float* K = (const float*)d_in[1];
    const float* V = (const float*)d_in[2];
    const int* vl  = (const int*)d_in[3];
    float* O = (float*)d_out;

    const size_t tensor_bytes = (size_t)NB * NTILE * 2 * 4096 * sizeof(short); // 16.78 MB
    const size_t need = 2 * tensor_bytes;

    if (ws_size >= need) {
        short* KWS = (short*)d_ws;
        short* VWS = KWS + (size_t)NB * NTILE * 2 * 4096;
        prep_k<<<dim3(NB * NTILE), dim3(512), 0, stream>>>(K, KWS);
        prep_v<<<dim3(NB * NTILE), dim3(512), 0, stream>>>(V, VWS);
        attn_fwd<<<dim3(NB * (NL / QT)), dim3(256), 0, stream>>>(Q, vl, KWS, VWS, O);
    } else {
        attn_fwd_fb<<<dim3(NB * (NL / QT)), dim3(256), 0, stream>>>(Q, K, V, vl, O);
    }
}